// Round 3
// baseline (184.778 us; speedup 1.0000x reference)
//
#include <hip/hip_runtime.h>
#include <stdint.h>

// Geometry: B=16, E=H=1024, H4=4096, K_total = E+H = 2048. All f32.
//
// Overhead model (rounds 0-2): harness adds ~156 us fixed per iteration
// (256 MiB workspace poison fill @40 us + ~116 us of resets/gaps),
// unconditional. dur_us = 156 + our kernels. Round-2 kernels ~27 us.
//
// k1 redesign ("row-band"): block = (s, q); s = K-slice of 32 rows
// (0..31 -> Wi/x, 32..63 -> Wh/h), q = contiguous 512-col band.
// A wave reads 512 B CONTIGUOUS W per load inst (float2/lane) walking rows,
// vs round-2's scattered 128 B col-tiles -- better DRAM streaming, and
// unroll-16 keeps ~8 KB/wave of loads in flight (<= 64 KB/CU, above the
// ~22 KB BW*latency product). 512 blocks = 2/CU, 8 waves/CU.
// q = bl & 7: each XCD's blocks cover one 512-col stripe of Wi+Wh = 4 MB
// = its private L2.
#define H4_ 4096
#define B_  16
#define SPLITS_ 64   // 32 K-rows per split; part = [64][16][4096] f32 = 16 MB

// ---- K1: row-band partial GEMM. grid = 512 x 256 thr.
__global__ __launch_bounds__(256) void k1_gemm(
    const float* __restrict__ x, const float* __restrict__ h,
    const float* __restrict__ Wi, const float* __restrict__ Wh,
    float* __restrict__ part)
{
    __shared__ float a_lds[32][16];      // 2 KB: a_lds[r][b] = A[b][e0+r]

    const int bl = blockIdx.x;
    const int q  = bl & 7;               // col band: 512 cols
    const int s  = bl >> 3;              // K-slice 0..63
    const int t  = threadIdx.x;

    const float* A = (s < 32) ? x : h;   // [16][1024]
    const float* W = (s < 32) ? Wi : Wh; // [1024][4096]
    const int e0 = (s & 31) * 32;        // first row of slice

    // stage A^T slice (512 floats, 2 per thread; uncoalesced but tiny & L2-hot)
    {
        const int b = t & 15, r0 = t >> 4;        // r0 in 0..15
        a_lds[r0][b]      = A[b * 1024 + e0 + r0];
        a_lds[r0 + 16][b] = A[b * 1024 + e0 + r0 + 16];
    }
    __syncthreads();

    const int j = q * 512 + t * 2;                // this thread's 2 cols
    const float* wp = W + (size_t)e0 * H4_ + j;

    float2 acc[16];
    #pragma unroll
    for (int b = 0; b < 16; b++) acc[b] = make_float2(0.f, 0.f);

    #pragma unroll 16
    for (int kl = 0; kl < 32; kl++) {
        const float2 w  = *(const float2*)(wp + (size_t)kl * H4_); // 512B/wave
        const float4 a0 = *(const float4*)&a_lds[kl][0];   // uniform addr ->
        const float4 a1 = *(const float4*)&a_lds[kl][4];   // LDS broadcast,
        const float4 a2 = *(const float4*)&a_lds[kl][8];   // zero conflicts
        const float4 a3 = *(const float4*)&a_lds[kl][12];
        const float av[16] = { a0.x,a0.y,a0.z,a0.w, a1.x,a1.y,a1.z,a1.w,
                               a2.x,a2.y,a2.z,a2.w, a3.x,a3.y,a3.z,a3.w };
        #pragma unroll
        for (int b = 0; b < 16; b++) {
            acc[b].x += av[b] * w.x;
            acc[b].y += av[b] * w.y;
        }
    }

    // part[s][b][j] — dwordx2 stores, 512 B/wave contiguous
    float* dst = part + (size_t)s * B_ * H4_ + j;
    #pragma unroll
    for (int b = 0; b < 16; b++)
        *(float2*)(dst + (size_t)b * H4_) = acc[b];
}

// ---- K2: sum 64 split partials + biases, activations. grid = 256 x 256.
// Block = (batch b, 64-col j-window) x 4 gates in threads; partial loads are
// 256 B/wave coalesced and L2/L3-warm (part was just written).
__global__ __launch_bounds__(256) void k2_act(
    const float* __restrict__ part, const float* __restrict__ c,
    const float* __restrict__ Wi_b, const float* __restrict__ Wh_b,
    float* __restrict__ out)
{
    __shared__ float gl[4][64];

    const int blk = blockIdx.x;          // 0..255
    const int b   = blk >> 4;            // batch 0..15
    const int j0  = (blk & 15) * 64;     // col window
    const int t   = threadIdx.x;
    const int g   = t >> 6, jj = t & 63;
    const int col = g * 1024 + j0 + jj;

    float acc = Wi_b[col] + Wh_b[col];
    const float* pp = part + (size_t)b * H4_ + col;
    #pragma unroll 16
    for (int ss = 0; ss < SPLITS_; ss++)
        acc += pp[(size_t)ss * B_ * H4_];
    gl[g][jj] = acc;
    __syncthreads();

    if (t < 64) {
        const int j = j0 + t;
        const float s0 = gl[0][t], s1 = gl[1][t], s2 = gl[2][t], s3 = gl[3][t];
        const float ig = 1.f / (1.f + __expf(-s0));
        const float fg = 1.f / (1.f + __expf(-s1));
        const float gg = tanhf(s2);
        const float og = 1.f / (1.f + __expf(-s3));
        const float cv = c[b * 1024 + j];
        const float cn = fg * cv + ig * gg;
        const float hn = og * tanhf(cn);
        out[b * 1024 + j]         = hn;   // h_new
        out[16384 + b * 1024 + j] = cn;   // c_new
    }
}

// ---- Fallback: fully fused, zero workspace (round-1 kernel, known-correct).
__global__ __launch_bounds__(256) void k_fused2(
    const float* __restrict__ x, const float* __restrict__ h,
    const float* __restrict__ cin,
    const float* __restrict__ Wi, const float* __restrict__ Wh,
    const float* __restrict__ Wi_b, const float* __restrict__ Wh_b,
    float* __restrict__ out)
{
    __shared__ float a_lds[256][16];
    __shared__ float red[16][16][16];
    __shared__ float gsum[16][16];

    const int bl = blockIdx.x;
    const int j0 = (bl & 7) * 128 + (bl >> 3) * 4;
    const int t  = threadIdx.x;
    const int g  = t & 3;
    const int bq = (t >> 2) & 3;
    const int ks = t >> 4;

    float acc[4][4];
    #pragma unroll
    for (int r = 0; r < 4; r++)
        #pragma unroll
        for (int c = 0; c < 4; c++) acc[r][c] = 0.f;

    for (int m = 0; m < 8; ++m) {
        const float* A  = (m < 4) ? x : h;
        const float* W  = (m < 4) ? Wi : Wh;
        const int    e0 = (m & 3) * 256;
        {
            const int b = t & 15, kc = t >> 4;
            const float* src = A + b * 1024 + e0 + kc * 16;
            float4 v0 = *(const float4*)(src);
            float4 v1 = *(const float4*)(src + 4);
            float4 v2 = *(const float4*)(src + 8);
            float4 v3 = *(const float4*)(src + 12);
            const float vv[16] = { v0.x, v0.y, v0.z, v0.w, v1.x, v1.y, v1.z, v1.w,
                                   v2.x, v2.y, v2.z, v2.w, v3.x, v3.y, v3.z, v3.w };
            #pragma unroll
            for (int jj = 0; jj < 16; jj++) a_lds[kc * 16 + jj][b] = vv[jj];
        }
        __syncthreads();
        const float* wp = W + (size_t)e0 * H4_ + g * 1024 + j0;
        #pragma unroll 4
        for (int i = 0; i < 16; i++) {
            const int kl = ks * 16 + i;
            float4 w = *(const float4*)(wp + (size_t)kl * H4_);
            float4 a = *(const float4*)&a_lds[kl][bq * 4];
            acc[0][0] += a.x * w.x; acc[0][1] += a.x * w.y; acc[0][2] += a.x * w.z; acc[0][3] += a.x * w.w;
            acc[1][0] += a.y * w.x; acc[1][1] += a.y * w.y; acc[1][2] += a.y * w.z; acc[1][3] += a.y * w.w;
            acc[2][0] += a.z * w.x; acc[2][1] += a.z * w.y; acc[2][2] += a.z * w.z; acc[2][3] += a.z * w.w;
            acc[3][0] += a.w * w.x; acc[3][1] += a.w * w.y; acc[3][2] += a.w * w.z; acc[3][3] += a.w * w.w;
        }
        __syncthreads();
    }

    #pragma unroll
    for (int r = 0; r < 4; r++)
        *(float4*)&red[ks][bq * 4 + r][g * 4] =
            make_float4(acc[r][0], acc[r][1], acc[r][2], acc[r][3]);
    __syncthreads();
    {
        const int b = t >> 4, c16 = t & 15;
        float sum = 0.f;
        #pragma unroll
        for (int kk = 0; kk < 16; kk++) sum += red[kk][b][c16];
        gsum[b][c16] = sum;
    }
    __syncthreads();

    if (t < 64) {
        const int b = t >> 2, jj = t & 3;
        const int j = j0 + jj;
        const float s0 = gsum[b][jj]      + Wi_b[j]        + Wh_b[j];
        const float s1 = gsum[b][4 + jj]  + Wi_b[1024 + j] + Wh_b[1024 + j];
        const float s2 = gsum[b][8 + jj]  + Wi_b[2048 + j] + Wh_b[2048 + j];
        const float s3 = gsum[b][12 + jj] + Wi_b[3072 + j] + Wh_b[3072 + j];
        const float ig = 1.f / (1.f + __expf(-s0));
        const float fg = 1.f / (1.f + __expf(-s1));
        const float gg = tanhf(s2);
        const float og = 1.f / (1.f + __expf(-s3));
        const float cv = cin[b * 1024 + j];
        const float cn = fg * cv + ig * gg;
        const float hn = og * tanhf(cn);
        out[b * 1024 + j]         = hn;
        out[16384 + b * 1024 + j] = cn;
    }
}

extern "C" void kernel_launch(void* const* d_in, const int* in_sizes, int n_in,
                              void* d_out, int out_size, void* d_ws, size_t ws_size,
                              hipStream_t stream) {
    (void)in_sizes; (void)n_in; (void)out_size;
    const float* x    = (const float*)d_in[0];
    const float* h    = (const float*)d_in[1];
    const float* c    = (const float*)d_in[2];
    // d_in[3] = context (dead: multiplied by 0 in reference)
    const float* Wi   = (const float*)d_in[4];
    const float* Wi_b = (const float*)d_in[5];
    const float* Wh   = (const float*)d_in[6];
    const float* Wh_b = (const float*)d_in[7];
    // d_in[8..11] = AZ_* (dead)

    float* part = (float*)d_ws;
    float* out  = (float*)d_out;

    const size_t need = (size_t)SPLITS_ * B_ * H4_ * sizeof(float);  // 16 MB
    if (ws_size >= need) {
        k1_gemm<<<512, 256, 0, stream>>>(x, h, Wi, Wh, part);
        k2_act<<<256, 256, 0, stream>>>(part, c, Wi_b, Wh_b, out);
    } else {
        k_fused2<<<64 * 4, 256, 0, stream>>>(x, h, c, Wi, Wh, Wi_b, Wh_b, out);
    }
}